// Round 2
// baseline (320.569 us; speedup 1.0000x reference)
//
#include <hip/hip_runtime.h>
#include <hip/hip_bf16.h>
#include <hip/hip_fp16.h>
#include <math.h>

#define N_NODES 10000
#define N_EDGES 160000
#define IN_CH 128
#define EMB 64
#define HEADS 12
#define NEG_SLOPE 0.2f
#define NPB 16  // nodes per block in projection

// ---------- kernel 1: emb = relu(x @ We + be) ----------
__global__ __launch_bounds__(256) void embed_kernel(
    const float* __restrict__ x, const float* __restrict__ We,
    const float* __restrict__ be, float* __restrict__ emb, int nNodes) {
  int gid = blockIdx.x * 256 + threadIdx.x;
  int n = gid >> 6, j = gid & 63;
  if (n >= nNodes) return;
  float s = be[j];
  const float* xr = x + (long)n * IN_CH;
  #pragma unroll 8
  for (int k = 0; k < IN_CH; ++k) s += xr[k] * We[k * EMB + j];
  emb[gid] = fmaxf(s, 0.f);
}

// ---------- kernel 2: hh(half) = emb @ W ; a_src/a_dst per-head logits ----------
__global__ __launch_bounds__(768) void project_kernel(
    const float* __restrict__ emb, const float* __restrict__ W,
    const float* __restrict__ att_src, const float* __restrict__ att_dst,
    __half* __restrict__ hh, float* __restrict__ a_src, float* __restrict__ a_dst,
    int nNodes) {
  const int t = threadIdx.x;          // t = h*64 + d
  const int h = t >> 6, d = t & 63;
  const int n0 = blockIdx.x * NPB;
  __shared__ float emb_s[NPB][EMB];
  {
    // 768 threads load 16*64=1024 values in 2 strided steps
    for (int i = t; i < NPB * EMB; i += 768) {
      int nn = n0 + (i >> 6);
      emb_s[i >> 6][i & 63] = (nn < nNodes) ? emb[(long)nn * EMB + (i & 63)] : 0.f;
    }
  }
  __syncthreads();
  float val[NPB];
  #pragma unroll
  for (int i = 0; i < NPB; ++i) val[i] = 0.f;
  for (int k = 0; k < EMB; ++k) {
    float w = W[k * (HEADS * EMB) + t];
    #pragma unroll
    for (int i = 0; i < NPB; ++i) val[i] += emb_s[i][k] * w;
  }
  const float asv = att_src[t];  // att_src[h][d] flat == index t
  const float adv = att_dst[t];
  for (int i = 0; i < NPB; ++i) {
    int n = n0 + i;
    if (n >= nNodes) break;
    hh[(long)n * (HEADS * EMB) + t] = __float2half(val[i]);
    float rs = val[i] * asv;
    float rd = val[i] * adv;
    #pragma unroll
    for (int off = 32; off > 0; off >>= 1) {
      rs += __shfl_down(rs, off, 64);
      rd += __shfl_down(rd, off, 64);
    }
    if (d == 0) {
      a_src[n * HEADS + h] = rs;
      a_dst[n * HEADS + h] = rd;
    }
  }
}

// ---------- CSR build ----------
__global__ void zero_kernel(int* deg, int* cursor, int n) {
  int i = blockIdx.x * 256 + threadIdx.x;
  if (i < n) { deg[i] = 0; cursor[i] = 0; }
}

__global__ void count_kernel(const int* __restrict__ ei, int* __restrict__ deg,
                             int nE, int nN) {
  int e = blockIdx.x * 256 + threadIdx.x;
  if (e >= nE + nN) return;
  int dst = (e < nE) ? ei[nE + e] : (e - nE);  // self-loop for e >= nE
  atomicAdd(&deg[dst], 1);
}

// 1024 threads, 10 elements/thread, wave-shuffle scan. 3 barriers total.
__global__ __launch_bounds__(1024) void scan_kernel(
    const int* __restrict__ deg, int* __restrict__ row_start, int n) {
  const int tid = threadIdx.x;
  const int lane = tid & 63, wv = tid >> 6;  // 16 waves
  int pre[10];
  int s = 0;
  const int base = tid * 10;
  #pragma unroll
  for (int j = 0; j < 10; ++j) {
    int i = base + j;
    int v = (i < n) ? deg[i] : 0;
    pre[j] = s;
    s += v;
  }
  // wave inclusive scan of per-thread totals
  int sc = s;
  #pragma unroll
  for (int off = 1; off < 64; off <<= 1) {
    int t2 = __shfl_up(sc, off, 64);
    if (lane >= off) sc += t2;
  }
  __shared__ int wsum[16];
  __shared__ int woff[17];
  if (lane == 63) wsum[wv] = sc;
  __syncthreads();
  if (tid == 0) {
    int a = 0;
    for (int w = 0; w < 16; ++w) { woff[w] = a; a += wsum[w]; }
    woff[16] = a;
  }
  __syncthreads();
  const int excl = woff[wv] + (sc - s);  // exclusive prefix of this thread
  #pragma unroll
  for (int j = 0; j < 10; ++j) {
    int i = base + j;
    if (i < n) row_start[i] = excl + pre[j];
  }
  if (tid == 0) row_start[n] = woff[16];
}

__global__ void fill_kernel(const int* __restrict__ ei,
                            const int* __restrict__ row_start,
                            int* __restrict__ cursor, int* __restrict__ csr_src,
                            int nE, int nN) {
  int e = blockIdx.x * 256 + threadIdx.x;
  if (e >= nE + nN) return;
  int src, dst;
  if (e < nE) { src = ei[e]; dst = ei[nE + e]; }
  else        { src = e - nE; dst = e - nE; }
  int pos = atomicAdd(&cursor[dst], 1);
  csr_src[row_start[dst] + pos] = src;
}

// ---------- kernel 3: per-dst gather, online softmax, barrier-free main loop ----------
__global__ __launch_bounds__(768) void gat_gather(
    const __half* __restrict__ hh, const float* __restrict__ a_src,
    const float* __restrict__ a_dst, const float* __restrict__ emb,
    const float* __restrict__ bias, const int* __restrict__ row_start,
    const int* __restrict__ csr_src, float* __restrict__ out) {
  const int n = blockIdx.x;
  const int t = threadIdx.x;          // t = h*64 + d ; wave index == head
  const int h = t >> 6, d = t & 63;
  const float adst = a_dst[n * HEADS + h];
  const int e0 = row_start[n];
  const int deg = row_start[n + 1] - e0;

  float m = -1e30f, l = 0.f, acc = 0.f;

  for (int base = 0; base < deg; base += 64) {
    const int csize = min(64, deg - base);
    int src = 0;
    float e = -1e30f;
    if (d < csize) {
      src = csr_src[e0 + base + d];
      float lg = a_src[src * HEADS + h] + adst;
      e = (lg > 0.f) ? lg : NEG_SLOPE * lg;
    }
    // chunk max (all lanes end with the max)
    float cm = e;
    #pragma unroll
    for (int off = 32; off > 0; off >>= 1) cm = fmaxf(cm, __shfl_xor(cm, off, 64));
    const float nm = fmaxf(m, cm);
    const float scale = __expf(m - nm);  // first chunk: exp(-huge)=0
    float w = (d < csize) ? __expf(e - nm) : 0.f;
    float cs = w;
    #pragma unroll
    for (int off = 32; off > 0; off >>= 1) cs += __shfl_xor(cs, off, 64);
    l = l * scale + cs;
    acc *= scale;
    m = nm;
    #pragma unroll 4
    for (int i = 0; i < csize; ++i) {
      int si = __shfl(src, i, 64);
      float wi = __shfl(w, i, 64);
      acc += wi * __half2float(hh[(long)si * (HEADS * EMB) + (h << 6) + d]);
    }
  }

  // epilogue: normalize, head-mean, +bias, residual relu
  __shared__ float ybuf[HEADS * 64];
  ybuf[t] = acc / (l + 1e-16f);
  __syncthreads();
  if (t < 64) {
    float s = 0.f;
    #pragma unroll
    for (int hi = 0; hi < HEADS; ++hi) s += ybuf[hi * 64 + t];
    float yv = s * (1.f / HEADS) + bias[t];
    float r = emb[(long)n * EMB + t] + yv;
    out[(long)n * EMB + t] = fmaxf(r, 0.f);
  }
}

extern "C" void kernel_launch(void* const* d_in, const int* in_sizes, int n_in,
                              void* d_out, int out_size, void* d_ws, size_t ws_size,
                              hipStream_t stream) {
  const float* x       = (const float*)d_in[0];
  const int*   ei      = (const int*)  d_in[1];
  const float* We      = (const float*)d_in[2];
  const float* be      = (const float*)d_in[3];
  const float* W       = (const float*)d_in[4];
  const float* att_src = (const float*)d_in[5];
  const float* att_dst = (const float*)d_in[6];
  const float* bias    = (const float*)d_in[7];
  float* out = (float*)d_out;

  // workspace layout
  float* emb    = (float*)d_ws;                       // 640000 f32
  float* a_src  = emb + (long)N_NODES * EMB;          // 120000 f32
  float* a_dst  = a_src + N_NODES * HEADS;            // 120000 f32
  int*   deg    = (int*)(a_dst + N_NODES * HEADS);    // 10000
  int*   row_st = deg + N_NODES;                      // 10001
  int*   cursor = row_st + N_NODES + 1;               // 10000
  int*   csr    = cursor + N_NODES;                   // 170000
  __half* hh    = (__half*)(csr + (N_EDGES + N_NODES)); // 7,680,000 half

  const int nTot = N_EDGES + N_NODES;

  embed_kernel<<<(N_NODES * EMB + 255) / 256, 256, 0, stream>>>(x, We, be, emb, N_NODES);
  project_kernel<<<(N_NODES + NPB - 1) / NPB, 768, 0, stream>>>(
      emb, W, att_src, att_dst, hh, a_src, a_dst, N_NODES);
  zero_kernel<<<(N_NODES + 255) / 256, 256, 0, stream>>>(deg, cursor, N_NODES);
  count_kernel<<<(nTot + 255) / 256, 256, 0, stream>>>(ei, deg, N_EDGES, N_NODES);
  scan_kernel<<<1, 1024, 0, stream>>>(deg, row_st, N_NODES);
  fill_kernel<<<(nTot + 255) / 256, 256, 0, stream>>>(ei, row_st, cursor, csr, N_EDGES, N_NODES);
  gat_gather<<<N_NODES, 768, 0, stream>>>(hh, a_src, a_dst, emb, bias, row_st, csr, out);
}

// Round 3
// 234.348 us; speedup vs baseline: 1.3679x; 1.3679x over previous
//
#include <hip/hip_runtime.h>
#include <hip/hip_bf16.h>
#include <hip/hip_fp16.h>
#include <math.h>

#define N_NODES 10000
#define N_EDGES 160000
#define IN_CH 128
#define EMB 64
#define HEADS 12
#define NEG_SLOPE 0.2f
#define NPB 16  // nodes per block in fused embed+project (10000/16 = 625 exact)

// ---------- kernel 1 (fused): emb = relu(x@We+be); hh(half) = emb@W; a_src/a_dst ----------
__global__ __launch_bounds__(768) void embed_project_kernel(
    const float* __restrict__ x, const float* __restrict__ We,
    const float* __restrict__ be, const float* __restrict__ W,
    const float* __restrict__ att_src, const float* __restrict__ att_dst,
    float* __restrict__ emb, __half* __restrict__ hh,
    float* __restrict__ a_src, float* __restrict__ a_dst, int nNodes) {
  const int t = threadIdx.x;          // t = h*64 + d
  const int h = t >> 6, d = t & 63;
  const int n0 = blockIdx.x * NPB;
  __shared__ float x_s[NPB][IN_CH];   // 8 KB
  __shared__ float emb_s[NPB][EMB];   // 4 KB

  // stage x rows (coalesced)
  for (int i = t; i < NPB * IN_CH; i += 768) {
    int nn = n0 + (i >> 7);
    x_s[i >> 7][i & 127] = (nn < nNodes) ? x[(long)nn * IN_CH + (i & 127)] : 0.f;
  }
  __syncthreads();

  // phase A: emb rows for these NPB nodes
  for (int o = t; o < NPB * EMB; o += 768) {
    int i = o >> 6, j = o & 63;
    float s = be[j];
    #pragma unroll 8
    for (int k = 0; k < IN_CH; ++k) s += x_s[i][k] * We[k * EMB + j];
    s = fmaxf(s, 0.f);
    emb_s[i][j] = s;
    int nn = n0 + i;
    if (nn < nNodes) emb[(long)nn * EMB + j] = s;
  }
  __syncthreads();

  // phase B: project to per-head features + attention logits
  float val[NPB];
  #pragma unroll
  for (int i = 0; i < NPB; ++i) val[i] = 0.f;
  for (int k = 0; k < EMB; ++k) {
    float w = W[k * (HEADS * EMB) + t];
    #pragma unroll
    for (int i = 0; i < NPB; ++i) val[i] += emb_s[i][k] * w;
  }
  const float asv = att_src[t];
  const float adv = att_dst[t];
  for (int i = 0; i < NPB; ++i) {
    int n = n0 + i;
    if (n >= nNodes) break;
    hh[(long)n * (HEADS * EMB) + t] = __float2half(val[i]);
    float rs = val[i] * asv;
    float rd = val[i] * adv;
    #pragma unroll
    for (int off = 32; off > 0; off >>= 1) {
      rs += __shfl_down(rs, off, 64);
      rd += __shfl_down(rd, off, 64);
    }
    if (d == 0) {
      a_src[n * HEADS + h] = rs;
      a_dst[n * HEADS + h] = rd;
    }
  }
}

// ---------- CSR build ----------
__global__ void count_kernel(const int* __restrict__ ei, int* __restrict__ deg,
                             int nE, int nN) {
  int e = blockIdx.x * 256 + threadIdx.x;
  if (e >= nE + nN) return;
  int dst = (e < nE) ? ei[nE + e] : (e - nE);  // self-loop for e >= nE
  atomicAdd(&deg[dst], 1);
}

// 1024 threads, 10 elements/thread, wave-shuffle scan. 3 barriers total.
__global__ __launch_bounds__(1024) void scan_kernel(
    const int* __restrict__ deg, int* __restrict__ row_start, int n) {
  const int tid = threadIdx.x;
  const int lane = tid & 63, wv = tid >> 6;  // 16 waves
  int pre[10];
  int s = 0;
  const int base = tid * 10;
  #pragma unroll
  for (int j = 0; j < 10; ++j) {
    int i = base + j;
    int v = (i < n) ? deg[i] : 0;
    pre[j] = s;
    s += v;
  }
  int sc = s;
  #pragma unroll
  for (int off = 1; off < 64; off <<= 1) {
    int t2 = __shfl_up(sc, off, 64);
    if (lane >= off) sc += t2;
  }
  __shared__ int wsum[16];
  __shared__ int woff[17];
  if (lane == 63) wsum[wv] = sc;
  __syncthreads();
  if (tid == 0) {
    int a = 0;
    for (int w = 0; w < 16; ++w) { woff[w] = a; a += wsum[w]; }
    woff[16] = a;
  }
  __syncthreads();
  const int excl = woff[wv] + (sc - s);
  #pragma unroll
  for (int j = 0; j < 10; ++j) {
    int i = base + j;
    if (i < n) row_start[i] = excl + pre[j];
  }
  if (tid == 0) row_start[n] = woff[16];
}

__global__ void fill_kernel(const int* __restrict__ ei,
                            const int* __restrict__ row_start,
                            int* __restrict__ cursor, int* __restrict__ csr_src,
                            int nE, int nN) {
  int e = blockIdx.x * 256 + threadIdx.x;
  if (e >= nE + nN) return;
  int src, dst;
  if (e < nE) { src = ei[e]; dst = ei[nE + e]; }
  else        { src = e - nE; dst = e - nE; }
  int pos = atomicAdd(&cursor[dst], 1);
  csr_src[row_start[dst] + pos] = src;
}

// ---------- kernel 3: per-dst gather, online softmax, pair-mapped half2 loads ----------
__global__ __launch_bounds__(768) void gat_gather(
    const __half* __restrict__ hh, const float* __restrict__ a_src,
    const float* __restrict__ a_dst, const float* __restrict__ emb,
    const float* __restrict__ bias, const int* __restrict__ row_start,
    const int* __restrict__ csr_src, float* __restrict__ out) {
  const int n = blockIdx.x;
  const int t = threadIdx.x;          // t = h*64 + lane ; wave == head
  const int h = t >> 6, lane = t & 63;
  const int sub = lane >> 5, d2 = lane & 31;  // pair mapping: edge parity, dim pair
  const float adst = a_dst[n * HEADS + h];
  const int e0 = row_start[n];
  const int deg = row_start[n + 1] - e0;

  __shared__ float w_s[HEADS][64];    // wave-private rows
  __shared__ int   off_s[HEADS][64];  // element offsets src*768

  float m = -1e30f, l = 0.f;
  float accx0 = 0.f, accy0 = 0.f, accx1 = 0.f, accy1 = 0.f;

  for (int base = 0; base < deg; base += 64) {
    const int csize = min(64, deg - base);
    int src = 0;
    float e = -1e30f;
    if (lane < csize) {
      src = csr_src[e0 + base + lane];
      float lg = a_src[src * HEADS + h] + adst;
      e = (lg > 0.f) ? lg : NEG_SLOPE * lg;
    }
    float cm = e;
    #pragma unroll
    for (int off = 32; off > 0; off >>= 1) cm = fmaxf(cm, __shfl_xor(cm, off, 64));
    const float nm = fmaxf(m, cm);
    const float scale = __expf(m - nm);
    float w = (lane < csize) ? __expf(e - nm) : 0.f;
    float cs = w;
    #pragma unroll
    for (int off = 32; off > 0; off >>= 1) cs += __shfl_xor(cs, off, 64);
    l = l * scale + cs;
    m = nm;
    accx0 *= scale; accy0 *= scale; accx1 *= scale; accy1 *= scale;

    // stage weights + offsets wave-private (no barrier needed: same wave RW)
    w_s[h][lane] = w;                       // w=0 for lane>=csize
    off_s[h][lane] = src * (HEADS * EMB);   // src=0 for lane>=csize (harmless)

    // pair-mapped accumulate: each instruction covers 2 dims x (2 edges across wave)
    const int dofs = (h << 6) + (d2 << 1);
    #pragma unroll 4
    for (int i = 0; i < csize; i += 4) {
      int ea = i + sub, eb = i + 2 + sub;
      float wa = w_s[h][ea]; int oa = off_s[h][ea];
      float wb = w_s[h][eb]; int ob = off_s[h][eb];
      __half2 va = *(const __half2*)(hh + oa + dofs);
      __half2 vb = *(const __half2*)(hh + ob + dofs);
      float2 fa = __half22float2(va);
      float2 fb = __half22float2(vb);
      accx0 += wa * fa.x; accy0 += wa * fa.y;
      accx1 += wb * fb.x; accy1 += wb * fb.y;
    }
  }

  // combine: sub=0 lanes hold even-edge sums, sub=1 odd-edge sums
  float ax = accx0 + accx1;
  float ay = accy0 + accy1;
  ax += __shfl_xor(ax, 32, 64);
  ay += __shfl_xor(ay, 32, 64);
  const float inv = 1.f / (l + 1e-16f);
  if (sub == 0) {                        // reuse w_s as y buffer [head][dim]
    w_s[h][2 * d2]     = ax * inv;
    w_s[h][2 * d2 + 1] = ay * inv;
  }
  __syncthreads();
  if (t < 64) {
    float s = 0.f;
    #pragma unroll
    for (int hi = 0; hi < HEADS; ++hi) s += w_s[hi][t];
    float yv = s * (1.f / HEADS) + bias[t];
    float r = emb[(long)n * EMB + t] + yv;
    out[(long)n * EMB + t] = fmaxf(r, 0.f);
  }
}

extern "C" void kernel_launch(void* const* d_in, const int* in_sizes, int n_in,
                              void* d_out, int out_size, void* d_ws, size_t ws_size,
                              hipStream_t stream) {
  const float* x       = (const float*)d_in[0];
  const int*   ei      = (const int*)  d_in[1];
  const float* We      = (const float*)d_in[2];
  const float* be      = (const float*)d_in[3];
  const float* W       = (const float*)d_in[4];
  const float* att_src = (const float*)d_in[5];
  const float* att_dst = (const float*)d_in[6];
  const float* bias    = (const float*)d_in[7];
  float* out = (float*)d_out;

  // workspace layout (deg+cursor adjacent for single memset)
  float* emb    = (float*)d_ws;                        // 640000 f32
  float* a_src  = emb + (long)N_NODES * EMB;           // 120000
  float* a_dst  = a_src + N_NODES * HEADS;             // 120000
  int*   deg    = (int*)(a_dst + N_NODES * HEADS);     // 10000
  int*   cursor = deg + N_NODES;                       // 10000
  int*   row_st = cursor + N_NODES;                    // 10001
  int*   csr    = row_st + N_NODES + 1;                // 170000
  __half* hh    = (__half*)(csr + (N_EDGES + N_NODES)); // 7,680,000 half

  const int nTot = N_EDGES + N_NODES;

  hipMemsetAsync(deg, 0, 2 * N_NODES * sizeof(int), stream);
  count_kernel<<<(nTot + 255) / 256, 256, 0, stream>>>(ei, deg, N_EDGES, N_NODES);
  scan_kernel<<<1, 1024, 0, stream>>>(deg, row_st, N_NODES);
  fill_kernel<<<(nTot + 255) / 256, 256, 0, stream>>>(ei, row_st, cursor, csr, N_EDGES, N_NODES);
  embed_project_kernel<<<(N_NODES + NPB - 1) / NPB, 768, 0, stream>>>(
      x, We, be, W, att_src, att_dst, emb, hh, a_src, a_dst, N_NODES);
  gat_gather<<<N_NODES, 768, 0, stream>>>(hh, a_src, a_dst, emb, bias, row_st, csr, out);
}